// Round 2
// baseline (555.107 us; speedup 1.0000x reference)
//
#include <hip/hip_runtime.h>

// y_pred: [B, PRED] fp32, y_ori: [B, T] fp32, SCALE = PRED/T = 4
#define B_ROWS   4096
#define T_LEN    2048
#define PRED_LEN 8192
#define NT       256
#define ITERS    (T_LEN / NT)   // 8 windows per thread

// Fused: per-row masked MSE + grid-level reduction via last-block-done.
__global__ __launch_bounds__(NT) void tsmal_fused_kernel(
    const float* __restrict__ y_pred,
    const float* __restrict__ y_ori,
    float* __restrict__ ws_loss,    // [B]
    float* __restrict__ ws_valid,   // [B]
    unsigned int* __restrict__ counter,
    float* __restrict__ out)
{
    __shared__ float s_ori[T_LEN];
    const int row = blockIdx.x;
    const int tid = threadIdx.x;

    // 1) Issue ALL y_pred loads first (8 x float4 per thread, coalesced).
    const float4* pred4 = reinterpret_cast<const float4*>(y_pred + (size_t)row * PRED_LEN);
    float4 p[ITERS];
    #pragma unroll
    for (int k = 0; k < ITERS; ++k)
        p[k] = pred4[tid + NT * k];

    // 2) Stage y_ori row into LDS (2 x float4 per thread) while pred loads fly.
    const float4* ori4 = reinterpret_cast<const float4*>(y_ori + (size_t)row * T_LEN);
    float4* s_ori4 = reinterpret_cast<float4*>(s_ori);
    #pragma unroll
    for (int j = 0; j < T_LEN / 4 / NT; ++j)
        s_ori4[tid + NT * j] = ori4[tid + NT * j];
    __syncthreads();

    // 3) Compute masked squared error per window.
    float sum = 0.0f;
    float cnt = 0.0f;
    #pragma unroll
    for (int k = 0; k < ITERS; ++k) {
        const int i = tid + NT * k;
        float wm = fmaxf(fmaxf(p[k].x, p[k].y), fmaxf(p[k].z, p[k].w));

        int im1 = (i >= 1) ? i - 1 : 0;
        int ip1 = (i <= T_LEN - 2) ? i + 1 : T_LEN - 1;
        float yc = s_ori[i];
        float dm = yc - s_ori[im1];           // diff[i-1]
        float dp = s_ori[ip1] - yc;           // diff[i]
        bool interior = (i >= 1) && (i <= T_LEN - 2);
        bool mask = interior && (dp * dm < 0.0f) && (dm > 0.0f);

        float d = wm - yc;
        sum += mask ? d * d : 0.0f;
        cnt += mask ? 1.0f : 0.0f;
    }

    // 4) Wave + cross-wave reduction.
    #pragma unroll
    for (int off = 32; off > 0; off >>= 1) {
        sum += __shfl_down(sum, off, 64);
        cnt += __shfl_down(cnt, off, 64);
    }
    __shared__ float s_sum[NT / 64];
    __shared__ float s_cnt[NT / 64];
    const int wave = tid >> 6;
    const int lane = tid & 63;
    if (lane == 0) { s_sum[wave] = sum; s_cnt[wave] = cnt; }
    __syncthreads();

    if (tid == 0) {
        float tsum = 0.0f, tcnt = 0.0f;
        #pragma unroll
        for (int w = 0; w < NT / 64; ++w) { tsum += s_sum[w]; tcnt += s_cnt[w]; }
        bool valid = tcnt > 0.0f;
        ws_loss[row]  = valid ? tsum / tcnt : 0.0f;
        ws_valid[row] = valid ? 1.0f : 0.0f;
    }

    // 5) Last-block-done grid reduction.
    __threadfence();                       // release ws_loss/ws_valid device-wide
    __shared__ bool s_last;
    if (tid == 0) {
        unsigned int ticket = atomicAdd(counter, 1u);
        s_last = (ticket == (unsigned int)(gridDim.x - 1));
    }
    __syncthreads();
    if (!s_last) return;
    __threadfence();                       // acquire: see all rows' results

    float total = 0.0f, nvalid = 0.0f;
    const float4* l4 = reinterpret_cast<const float4*>(ws_loss);
    const float4* v4 = reinterpret_cast<const float4*>(ws_valid);
    for (int j = tid; j < B_ROWS / 4; j += NT) {
        float4 a = l4[j];
        float4 b = v4[j];
        total  += a.x + a.y + a.z + a.w;
        nvalid += b.x + b.y + b.z + b.w;
    }
    #pragma unroll
    for (int off = 32; off > 0; off >>= 1) {
        total  += __shfl_down(total, off, 64);
        nvalid += __shfl_down(nvalid, off, 64);
    }
    __shared__ float s_tot[NT / 64];
    __shared__ float s_nv[NT / 64];
    if (lane == 0) { s_tot[wave] = total; s_nv[wave] = nvalid; }
    __syncthreads();
    if (tid == 0) {
        float t = 0.0f, nv = 0.0f;
        #pragma unroll
        for (int w = 0; w < NT / 64; ++w) { t += s_tot[w]; nv += s_nv[w]; }
        out[0] = (nv > 0.0f) ? t / nv : 0.0f;
    }
}

extern "C" void kernel_launch(void* const* d_in, const int* in_sizes, int n_in,
                              void* d_out, int out_size, void* d_ws, size_t ws_size,
                              hipStream_t stream) {
    const float* y_pred = (const float*)d_in[0];
    const float* y_ori  = (const float*)d_in[1];
    float* out = (float*)d_out;

    float* ws_loss  = (float*)d_ws;                     // [B_ROWS]
    float* ws_valid = ws_loss + B_ROWS;                 // [B_ROWS]
    unsigned int* counter = (unsigned int*)(ws_valid + B_ROWS);

    // Zero the ticket counter each call (graph-capturable memset node).
    hipMemsetAsync(counter, 0, sizeof(unsigned int), stream);

    tsmal_fused_kernel<<<B_ROWS, NT, 0, stream>>>(y_pred, y_ori, ws_loss, ws_valid,
                                                  counter, out);
}

// Round 3
// 31.928 us; speedup vs baseline: 17.3864x; 17.3864x over previous
//
#include <hip/hip_runtime.h>

// y_pred: [B, PRED] fp32, y_ori: [B, T] fp32, SCALE = PRED/T = 4
#define B_ROWS   4096
#define T_LEN    2048
#define PRED_LEN 8192
#define NT       256
#define ITERS    (T_LEN / NT)   // 8 windows per thread

// Kernel 1: per-row masked MSE over detected maxima. One block per row.
// All y_pred loads are issued before the y_ori LDS staging so both HBM
// streams are in flight concurrently (no dependent use until after barrier).
__global__ __launch_bounds__(NT) void tsmal_row_kernel(
    const float* __restrict__ y_pred,
    const float* __restrict__ y_ori,
    float2* __restrict__ ws_res)    // [B] (loss, valid)
{
    __shared__ float s_ori[T_LEN];
    const int row = blockIdx.x;
    const int tid = threadIdx.x;

    // 1) Issue ALL y_pred loads first (8 x float4 per thread, coalesced).
    const float4* pred4 = reinterpret_cast<const float4*>(y_pred + (size_t)row * PRED_LEN);
    float4 p[ITERS];
    #pragma unroll
    for (int k = 0; k < ITERS; ++k)
        p[k] = pred4[tid + NT * k];

    // 2) Stage y_ori row into LDS (2 x float4 per thread) while pred loads fly.
    const float4* ori4 = reinterpret_cast<const float4*>(y_ori + (size_t)row * T_LEN);
    float4* s_ori4 = reinterpret_cast<float4*>(s_ori);
    #pragma unroll
    for (int j = 0; j < T_LEN / 4 / NT; ++j)
        s_ori4[tid + NT * j] = ori4[tid + NT * j];
    __syncthreads();

    // 3) Masked squared error per window.
    float sum = 0.0f;
    float cnt = 0.0f;
    #pragma unroll
    for (int k = 0; k < ITERS; ++k) {
        const int i = tid + NT * k;
        float wm = fmaxf(fmaxf(p[k].x, p[k].y), fmaxf(p[k].z, p[k].w));

        int im1 = (i >= 1) ? i - 1 : 0;
        int ip1 = (i <= T_LEN - 2) ? i + 1 : T_LEN - 1;
        float yc = s_ori[i];
        float dm = yc - s_ori[im1];           // diff[i-1]
        float dp = s_ori[ip1] - yc;           // diff[i]
        bool interior = (i >= 1) && (i <= T_LEN - 2);
        bool mask = interior && (dp * dm < 0.0f) && (dm > 0.0f);

        float d = wm - yc;
        sum += mask ? d * d : 0.0f;
        cnt += mask ? 1.0f : 0.0f;
    }

    // 4) Wave + cross-wave reduction.
    #pragma unroll
    for (int off = 32; off > 0; off >>= 1) {
        sum += __shfl_down(sum, off, 64);
        cnt += __shfl_down(cnt, off, 64);
    }
    __shared__ float s_sum[NT / 64];
    __shared__ float s_cnt[NT / 64];
    const int wave = tid >> 6;
    const int lane = tid & 63;
    if (lane == 0) { s_sum[wave] = sum; s_cnt[wave] = cnt; }
    __syncthreads();

    if (tid == 0) {
        float tsum = 0.0f, tcnt = 0.0f;
        #pragma unroll
        for (int w = 0; w < NT / 64; ++w) { tsum += s_sum[w]; tcnt += s_cnt[w]; }
        bool valid = tcnt > 0.0f;
        ws_res[row] = make_float2(valid ? tsum / tcnt : 0.0f, valid ? 1.0f : 0.0f);
    }
}

// Kernel 2: reduce per-row (loss, valid) pairs to the final scalar.
#define NT2 1024
__global__ __launch_bounds__(NT2) void tsmal_final_kernel(
    const float2* __restrict__ ws_res,
    float* __restrict__ out)
{
    const int tid = threadIdx.x;
    // 4096 float2 = 2048 float4; 1024 threads -> 2 float4 each.
    const float4* r4 = reinterpret_cast<const float4*>(ws_res);
    float total = 0.0f, nvalid = 0.0f;
    #pragma unroll
    for (int j = 0; j < 2; ++j) {
        float4 a = r4[tid + NT2 * j];
        total  += a.x + a.z;   // loss components
        nvalid += a.y + a.w;   // valid components
    }
    #pragma unroll
    for (int off = 32; off > 0; off >>= 1) {
        total  += __shfl_down(total, off, 64);
        nvalid += __shfl_down(nvalid, off, 64);
    }
    __shared__ float s_tot[NT2 / 64];
    __shared__ float s_nv[NT2 / 64];
    const int wave = tid >> 6;
    const int lane = tid & 63;
    if (lane == 0) { s_tot[wave] = total; s_nv[wave] = nvalid; }
    __syncthreads();
    if (tid == 0) {
        float t = 0.0f, nv = 0.0f;
        #pragma unroll
        for (int w = 0; w < NT2 / 64; ++w) { t += s_tot[w]; nv += s_nv[w]; }
        out[0] = (nv > 0.0f) ? t / nv : 0.0f;
    }
}

extern "C" void kernel_launch(void* const* d_in, const int* in_sizes, int n_in,
                              void* d_out, int out_size, void* d_ws, size_t ws_size,
                              hipStream_t stream) {
    const float* y_pred = (const float*)d_in[0];
    const float* y_ori  = (const float*)d_in[1];
    float* out = (float*)d_out;

    float2* ws_res = (float2*)d_ws;   // [B_ROWS] (loss, valid)

    tsmal_row_kernel<<<B_ROWS, NT, 0, stream>>>(y_pred, y_ori, ws_res);
    tsmal_final_kernel<<<1, NT2, 0, stream>>>(ws_res, out);
}

// Round 4
// 31.916 us; speedup vs baseline: 17.3930x; 1.0004x over previous
//
#include <hip/hip_runtime.h>

// y_pred: [B, PRED] fp32, y_ori: [B, T] fp32, SCALE = PRED/T = 4
#define B_ROWS   4096
#define T_LEN    2048
#define PRED_LEN 8192
#define NT       256
#define ITERS    (T_LEN / NT)   // 8 windows per thread

typedef __attribute__((address_space(3))) void       lds_void_t;
typedef __attribute__((address_space(1))) const void gbl_void_t;

// Kernel 1: per-row masked MSE over detected maxima. One block per row.
// y_ori is staged to LDS via global_load_lds (no VGPR round-trip); y_pred
// streams straight into registers. All 10 VMEM ops per thread are in flight
// before the single barrier.
__global__ __launch_bounds__(NT) void tsmal_row_kernel(
    const float* __restrict__ y_pred,
    const float* __restrict__ y_ori,
    float2* __restrict__ ws_res)    // [B] (loss, valid)
{
    __shared__ float s_ori[T_LEN];
    const int row  = blockIdx.x;
    const int tid  = threadIdx.x;
    const int wave = tid >> 6;
    const int lane = tid & 63;

    // 1) Async-stage y_ori row into LDS: 2 x 16B per thread.
    //    LDS dest is wave-uniform base + lane*16 (linear layout, matches HW).
    const float4* ori4   = reinterpret_cast<const float4*>(y_ori + (size_t)row * T_LEN);
    float4*       s_ori4 = reinterpret_cast<float4*>(s_ori);
    #pragma unroll
    for (int j = 0; j < T_LEN / 4 / NT; ++j) {
        const float4* gsrc = ori4 + (NT * j + tid);          // per-lane global src
        float4*       ldst = s_ori4 + (NT * j + wave * 64);  // wave-uniform base
        __builtin_amdgcn_global_load_lds((gbl_void_t*)gsrc, (lds_void_t*)ldst, 16, 0, 0);
    }

    // 2) Issue ALL y_pred loads (8 x float4 per thread, coalesced).
    const float4* pred4 = reinterpret_cast<const float4*>(y_pred + (size_t)row * PRED_LEN);
    float4 p[ITERS];
    #pragma unroll
    for (int k = 0; k < ITERS; ++k)
        p[k] = pred4[tid + NT * k];

    __syncthreads();   // drains vmcnt (pred + lds-stage) and publishes s_ori

    // 3) Masked squared error per window.
    float sum = 0.0f;
    float cnt = 0.0f;
    #pragma unroll
    for (int k = 0; k < ITERS; ++k) {
        const int i = tid + NT * k;
        float wm = fmaxf(fmaxf(p[k].x, p[k].y), fmaxf(p[k].z, p[k].w));

        int im1 = (i >= 1) ? i - 1 : 0;
        int ip1 = (i <= T_LEN - 2) ? i + 1 : T_LEN - 1;
        float yc = s_ori[i];
        float dm = yc - s_ori[im1];           // diff[i-1]
        float dp = s_ori[ip1] - yc;           // diff[i]
        bool interior = (i >= 1) && (i <= T_LEN - 2);
        bool mask = interior && (dp * dm < 0.0f) && (dm > 0.0f);

        float d = wm - yc;
        sum += mask ? d * d : 0.0f;
        cnt += mask ? 1.0f : 0.0f;
    }

    // 4) Wave + cross-wave reduction.
    #pragma unroll
    for (int off = 32; off > 0; off >>= 1) {
        sum += __shfl_down(sum, off, 64);
        cnt += __shfl_down(cnt, off, 64);
    }
    __shared__ float s_sum[NT / 64];
    __shared__ float s_cnt[NT / 64];
    if (lane == 0) { s_sum[wave] = sum; s_cnt[wave] = cnt; }
    __syncthreads();

    if (tid == 0) {
        float tsum = 0.0f, tcnt = 0.0f;
        #pragma unroll
        for (int w = 0; w < NT / 64; ++w) { tsum += s_sum[w]; tcnt += s_cnt[w]; }
        bool valid = tcnt > 0.0f;
        ws_res[row] = make_float2(valid ? tsum / tcnt : 0.0f, valid ? 1.0f : 0.0f);
    }
}

// Kernel 2: reduce per-row (loss, valid) pairs to the final scalar.
#define NT2 1024
__global__ __launch_bounds__(NT2) void tsmal_final_kernel(
    const float2* __restrict__ ws_res,
    float* __restrict__ out)
{
    const int tid = threadIdx.x;
    // 4096 float2 = 2048 float4; 1024 threads -> 2 float4 each.
    const float4* r4 = reinterpret_cast<const float4*>(ws_res);
    float total = 0.0f, nvalid = 0.0f;
    #pragma unroll
    for (int j = 0; j < 2; ++j) {
        float4 a = r4[tid + NT2 * j];
        total  += a.x + a.z;   // loss components
        nvalid += a.y + a.w;   // valid components
    }
    #pragma unroll
    for (int off = 32; off > 0; off >>= 1) {
        total  += __shfl_down(total, off, 64);
        nvalid += __shfl_down(nvalid, off, 64);
    }
    __shared__ float s_tot[NT2 / 64];
    __shared__ float s_nv[NT2 / 64];
    const int wave = tid >> 6;
    const int lane = tid & 63;
    if (lane == 0) { s_tot[wave] = total; s_nv[wave] = nvalid; }
    __syncthreads();
    if (tid == 0) {
        float t = 0.0f, nv = 0.0f;
        #pragma unroll
        for (int w = 0; w < NT2 / 64; ++w) { t += s_tot[w]; nv += s_nv[w]; }
        out[0] = (nv > 0.0f) ? t / nv : 0.0f;
    }
}

extern "C" void kernel_launch(void* const* d_in, const int* in_sizes, int n_in,
                              void* d_out, int out_size, void* d_ws, size_t ws_size,
                              hipStream_t stream) {
    const float* y_pred = (const float*)d_in[0];
    const float* y_ori  = (const float*)d_in[1];
    float* out = (float*)d_out;

    float2* ws_res = (float2*)d_ws;   // [B_ROWS] (loss, valid)

    tsmal_row_kernel<<<B_ROWS, NT, 0, stream>>>(y_pred, y_ori, ws_res);
    tsmal_final_kernel<<<1, NT2, 0, stream>>>(ws_res, out);
}